// Round 8
// baseline (268.992 us; speedup 1.0000x reference)
//
#include <hip/hip_runtime.h>
#include <hip/hip_bf16.h>

typedef short s16x8 __attribute__((ext_vector_type(8)));
typedef float f32x4 __attribute__((ext_vector_type(4)));
typedef unsigned short u16x8 __attribute__((ext_vector_type(8)));

static constexpr int Bc   = 8;
static constexpr int Nn   = 24576;
static constexpr int Kk   = 16;
static constexpr int Cc   = 64;
static constexpr int Rr   = Bc * Nn;     // 196608
static constexpr float EPS = 1e-5f;

__device__ __forceinline__ unsigned short f2bf(float f) {
    union { float f; unsigned int u; } c; c.f = f;
    unsigned int r = c.u + 0x7FFFu + ((c.u >> 16) & 1u);  // RNE
    return (unsigned short)(r >> 16);
}
__device__ __forceinline__ float bf2f(unsigned short u) {
    union { unsigned int u; float f; } c; c.u = ((unsigned int)u) << 16; return c.f;
}

// ---------------------------------------------------------------------------
// K1: h = x · W^T via MFMA (bf16 in, fp32 acc, bf16 out).
// XCD-batch partition: batch = bid%8. Block 0 zeroes the stats accumulator
// (stream order guarantees it's visible before K2's atomics).
// ---------------------------------------------------------------------------
__global__ __launch_bounds__(256) void linear_mfma_kernel(
    const float* __restrict__ x, const float* __restrict__ W,
    __hip_bfloat16* __restrict__ h, float* __restrict__ stats)
{
    if (blockIdx.x == 0 && threadIdx.x < 128) stats[threadIdx.x] = 0.f;

    const int tid  = threadIdx.x;
    const int l    = tid & 63;
    const int wave = tid >> 6;
    const int batch = blockIdx.x & 7;          // -> XCD (round-robin dispatch)
    const int qb    = blockIdx.x >> 3;         // 0..255
    const int wib   = qb * 4 + wave;           // wave-in-batch 0..1023

    const int lr = l & 15;
    const int kg = (l >> 4) * 8;
    const int dr = (l >> 4) * 4;

    s16x8 bfrag[4][2];
#pragma unroll
    for (int ct = 0; ct < 4; ++ct)
#pragma unroll
        for (int kc = 0; kc < 2; ++kc) {
            const float* bp = W + (ct * 16 + lr) * 64 + kc * 32 + kg;
            f32x4 b0 = *reinterpret_cast<const f32x4*>(bp);
            f32x4 b1 = *reinterpret_cast<const f32x4*>(bp + 4);
            s16x8 f;
            f[0] = (short)f2bf(b0[0]); f[1] = (short)f2bf(b0[1]);
            f[2] = (short)f2bf(b0[2]); f[3] = (short)f2bf(b0[3]);
            f[4] = (short)f2bf(b1[0]); f[5] = (short)f2bf(b1[1]);
            f[6] = (short)f2bf(b1[2]); f[7] = (short)f2bf(b1[3]);
            bfrag[ct][kc] = f;
        }

    unsigned short* hu = (unsigned short*)h;
    const int tiles_per_batch = Nn / 16;       // 1536
    for (int t = wib; t < tiles_per_batch; t += 1024) {
        const int row0 = batch * Nn + t * 16;
        const float* ap = x + (size_t)(row0 + lr) * 64 + kg;
        f32x4 a0 = *reinterpret_cast<const f32x4*>(ap);
        f32x4 a1 = *reinterpret_cast<const f32x4*>(ap + 4);
        f32x4 a2 = *reinterpret_cast<const f32x4*>(ap + 32);
        f32x4 a3 = *reinterpret_cast<const f32x4*>(ap + 36);
        s16x8 fa0, fa1;
        fa0[0] = (short)f2bf(a0[0]); fa0[1] = (short)f2bf(a0[1]);
        fa0[2] = (short)f2bf(a0[2]); fa0[3] = (short)f2bf(a0[3]);
        fa0[4] = (short)f2bf(a1[0]); fa0[5] = (short)f2bf(a1[1]);
        fa0[6] = (short)f2bf(a1[2]); fa0[7] = (short)f2bf(a1[3]);
        fa1[0] = (short)f2bf(a2[0]); fa1[1] = (short)f2bf(a2[1]);
        fa1[2] = (short)f2bf(a2[2]); fa1[3] = (short)f2bf(a2[3]);
        fa1[4] = (short)f2bf(a3[0]); fa1[5] = (short)f2bf(a3[1]);
        fa1[6] = (short)f2bf(a3[2]); fa1[7] = (short)f2bf(a3[3]);

        f32x4 acc[4];
#pragma unroll
        for (int ct = 0; ct < 4; ++ct) { acc[ct] = (f32x4){0.f, 0.f, 0.f, 0.f}; }
#pragma unroll
        for (int ct = 0; ct < 4; ++ct) {
            acc[ct] = __builtin_amdgcn_mfma_f32_16x16x32_bf16(fa0, bfrag[ct][0], acc[ct], 0, 0, 0);
            acc[ct] = __builtin_amdgcn_mfma_f32_16x16x32_bf16(fa1, bfrag[ct][1], acc[ct], 0, 0, 0);
        }
#pragma unroll
        for (int ct = 0; ct < 4; ++ct)
#pragma unroll
            for (int r = 0; r < 4; ++r)
                hu[(size_t)(row0 + dr + r) * 64 + ct * 16 + lr] = f2bf(acc[ct][r]);
    }
}

// ---------------------------------------------------------------------------
// K2: v[r][o] = (max_k h[nbr(r,k)][o]) - h[r][o], bf16 in/out.
// Round-6 structure (lane = channel, wave-uniform neighbor rows -> scalar
// saddr gathers) + 3-row ILP (48 gather lines in flight) + software
// pipelining of the knn-index / own-h loads (they head the dep chain and
// are cold-HBM / L2 respectively).
// batch = bid%8 keeps gathers on the XCD whose L2 holds the 3 MB h slice.
// ---------------------------------------------------------------------------
__global__ __launch_bounds__(256) void gather_bn_kernel(
    const __hip_bfloat16* __restrict__ h, const int* __restrict__ knn,
    __hip_bfloat16* __restrict__ v, float* __restrict__ stats)
{
    const int tid   = threadIdx.x;
    const int lane  = tid & 63;
    const int wave  = tid >> 6;
    const int batch = blockIdx.x & 7;
    const int qb    = blockIdx.x >> 3;
    const int wib   = qb * 4 + wave;           // 0..1023

    const unsigned short* hu = (const unsigned short*)h;
    unsigned short* vu = (unsigned short*)v;
    const int bbase = batch * Nn;
    const int kl    = lane & 15;

    float lsum = 0.f, lsq = 0.f;

    // 8 iterations x 3 rows; rows r, r+1, r+2 with r = wib*3 + it*3072
    int r = wib * 3;
    int i0 = knn[(size_t)(bbase + r + 0) * Kk + kl];
    int i1 = knn[(size_t)(bbase + r + 1) * Kk + kl];
    int i2 = knn[(size_t)(bbase + r + 2) * Kk + kl];
    unsigned short o0 = hu[(size_t)(bbase + r + 0) * 64 + lane];
    unsigned short o1 = hu[(size_t)(bbase + r + 1) * 64 + lane];
    unsigned short o2 = hu[(size_t)(bbase + r + 2) * 64 + lane];

    for (int it = 0; it < 8; ++it) {
        const int rn = r + 3072;
        int ni0 = 0, ni1 = 0, ni2 = 0;
        unsigned short no0 = 0, no1 = 0, no2 = 0;
        if (it < 7) {  // uniform branch: prefetch next iteration's heads
            ni0 = knn[(size_t)(bbase + rn + 0) * Kk + kl];
            ni1 = knn[(size_t)(bbase + rn + 1) * Kk + kl];
            ni2 = knn[(size_t)(bbase + rn + 2) * Kk + kl];
            no0 = hu[(size_t)(bbase + rn + 0) * 64 + lane];
            no1 = hu[(size_t)(bbase + rn + 1) * 64 + lane];
            no2 = hu[(size_t)(bbase + rn + 2) * 64 + lane];
        }

        float m0 = -3e38f, m1 = -3e38f, m2 = -3e38f;
#pragma unroll
        for (int k = 0; k < Kk; ++k) {
            const int j0 = __shfl(i0, k);      // wave-uniform -> saddr gather
            const int j1 = __shfl(i1, k);
            const int j2 = __shfl(i2, k);
            m0 = fmaxf(m0, bf2f(hu[(size_t)(bbase + j0) * 64 + lane]));
            m1 = fmaxf(m1, bf2f(hu[(size_t)(bbase + j1) * 64 + lane]));
            m2 = fmaxf(m2, bf2f(hu[(size_t)(bbase + j2) * 64 + lane]));
        }
        const float v0 = m0 - bf2f(o0);
        const float v1 = m1 - bf2f(o1);
        const float v2 = m2 - bf2f(o2);
        vu[(size_t)(bbase + r + 0) * 64 + lane] = f2bf(v0);
        vu[(size_t)(bbase + r + 1) * 64 + lane] = f2bf(v1);
        vu[(size_t)(bbase + r + 2) * 64 + lane] = f2bf(v2);
        lsum += v0 + v1 + v2;
        lsq  += v0 * v0 + v1 * v1 + v2 * v2;

        r = rn;
        i0 = ni0; i1 = ni1; i2 = ni2;
        o0 = no0; o1 = no1; o2 = no2;
    }

    __shared__ float s_sum[4][64];
    __shared__ float s_sq[4][64];
    s_sum[wave][lane] = lsum;
    s_sq[wave][lane]  = lsq;
    __syncthreads();
    if (wave == 0) {
        const float a = s_sum[0][lane] + s_sum[1][lane] + s_sum[2][lane] + s_sum[3][lane];
        const float q = s_sq[0][lane]  + s_sq[1][lane]  + s_sq[2][lane]  + s_sq[3][lane];
        atomicAdd(&stats[lane], a);
        atomicAdd(&stats[64 + lane], q);
    }
}

// ---------------------------------------------------------------------------
// K3: out = v_bf16 * scale[c] + shift[c]. scale/shift computed per-block
// from stats (trivial redundant work, saves a dispatch). Same batch
// partition: v read from the XCD L2 that K2 wrote through.
// ---------------------------------------------------------------------------
__global__ __launch_bounds__(256) void norm_kernel(
    const __hip_bfloat16* __restrict__ v, const float* __restrict__ stats,
    const float* __restrict__ gamma, const float* __restrict__ beta,
    float* __restrict__ out)
{
    __shared__ float sc[64], sh[64];
    if (threadIdx.x < 64) {
        const int o = threadIdx.x;
        const float inv = 1.0f / (float)Rr;
        const float mean = stats[o] * inv;
        const float var  = stats[64 + o] * inv - mean * mean;
        const float s    = gamma[o] * rsqrtf(var + EPS);
        sc[o] = s;
        sh[o] = beta[o] - mean * s;
    }
    __syncthreads();

    const int batch = blockIdx.x & 7;
    const int qb    = blockIdx.x >> 3;          // 0..255
    const u16x8* vu = (const u16x8*)v;
    const int per_batch8 = Nn * 64 / 8;         // groups of 8 elems per batch
    const size_t base8 = (size_t)batch * per_batch8;

    for (int li = qb * 256 + threadIdx.x; li < per_batch8; li += 256 * 256) {
        const size_t i = base8 + li;
        u16x8 t = vu[i];
        const int c = (li * 8) & 63;
        f32x4 r0, r1;
        r0[0] = bf2f(t[0]) * sc[c + 0] + sh[c + 0];
        r0[1] = bf2f(t[1]) * sc[c + 1] + sh[c + 1];
        r0[2] = bf2f(t[2]) * sc[c + 2] + sh[c + 2];
        r0[3] = bf2f(t[3]) * sc[c + 3] + sh[c + 3];
        r1[0] = bf2f(t[4]) * sc[c + 4] + sh[c + 4];
        r1[1] = bf2f(t[5]) * sc[c + 5] + sh[c + 5];
        r1[2] = bf2f(t[6]) * sc[c + 6] + sh[c + 6];
        r1[3] = bf2f(t[7]) * sc[c + 7] + sh[c + 7];
        f32x4* op = reinterpret_cast<f32x4*>(out + i * 8);
        __builtin_nontemporal_store(r0, op);
        __builtin_nontemporal_store(r1, op + 1);
    }
}

// ---------------------------------------------------------------------------
extern "C" void kernel_launch(void* const* d_in, const int* in_sizes, int n_in,
                              void* d_out, int out_size, void* d_ws, size_t ws_size,
                              hipStream_t stream)
{
    const float* x     = (const float*)d_in[0];
    const float* W     = (const float*)d_in[1];
    const float* gamma = (const float*)d_in[2];
    const float* beta  = (const float*)d_in[3];
    const int*   knn   = (const int*)d_in[4];
    float*       out   = (float*)d_out;

    // ws layout: h bf16 [Rr*64] | v bf16 [Rr*64] | stats[128]
    __hip_bfloat16* h = (__hip_bfloat16*)d_ws;
    __hip_bfloat16* v = h + (size_t)Rr * 64;
    float* stats = (float*)((char*)d_ws + 2 * (size_t)Rr * 64 * sizeof(__hip_bfloat16));

    linear_mfma_kernel<<<2048, 256, 0, stream>>>(x, W, h, stats);
    gather_bn_kernel<<<2048, 256, 0, stream>>>(h, knn, v, stats);
    norm_kernel<<<2048, 256, 0, stream>>>(v, stats, gamma, beta, out);
}

// Round 9
// 208.628 us; speedup vs baseline: 1.2893x; 1.2893x over previous
//
#include <hip/hip_runtime.h>
#include <hip/hip_bf16.h>

typedef short s16x8 __attribute__((ext_vector_type(8)));
typedef float f32x4 __attribute__((ext_vector_type(4)));
typedef unsigned short u16x8 __attribute__((ext_vector_type(8)));

static constexpr int Bc   = 8;
static constexpr int Nn   = 24576;
static constexpr int Kk   = 16;
static constexpr int Cc   = 64;
static constexpr int Rr   = Bc * Nn;     // 196608
static constexpr float EPS = 1e-5f;

__device__ __forceinline__ unsigned short f2bf(float f) {
    union { float f; unsigned int u; } c; c.f = f;
    unsigned int r = c.u + 0x7FFFu + ((c.u >> 16) & 1u);  // RNE
    return (unsigned short)(r >> 16);
}
__device__ __forceinline__ float bf2f(unsigned short u) {
    union { unsigned int u; float f; } c; c.u = ((unsigned int)u) << 16; return c.f;
}

// ---------------------------------------------------------------------------
// K1: h = x · W^T via MFMA (bf16 in, fp32 acc, bf16 out).
// XCD-batch partition: batch = bid%8. Block 0 zeroes the stats accumulator
// (stream order guarantees it's visible before K2's atomics).
// ---------------------------------------------------------------------------
__global__ __launch_bounds__(256) void linear_mfma_kernel(
    const float* __restrict__ x, const float* __restrict__ W,
    __hip_bfloat16* __restrict__ h, float* __restrict__ stats)
{
    if (blockIdx.x == 0 && threadIdx.x < 128) stats[threadIdx.x] = 0.f;

    const int tid  = threadIdx.x;
    const int l    = tid & 63;
    const int wave = tid >> 6;
    const int batch = blockIdx.x & 7;          // -> XCD (round-robin dispatch)
    const int qb    = blockIdx.x >> 3;         // 0..255
    const int wib   = qb * 4 + wave;           // wave-in-batch 0..1023

    const int lr = l & 15;
    const int kg = (l >> 4) * 8;
    const int dr = (l >> 4) * 4;

    s16x8 bfrag[4][2];
#pragma unroll
    for (int ct = 0; ct < 4; ++ct)
#pragma unroll
        for (int kc = 0; kc < 2; ++kc) {
            const float* bp = W + (ct * 16 + lr) * 64 + kc * 32 + kg;
            f32x4 b0 = *reinterpret_cast<const f32x4*>(bp);
            f32x4 b1 = *reinterpret_cast<const f32x4*>(bp + 4);
            s16x8 f;
            f[0] = (short)f2bf(b0[0]); f[1] = (short)f2bf(b0[1]);
            f[2] = (short)f2bf(b0[2]); f[3] = (short)f2bf(b0[3]);
            f[4] = (short)f2bf(b1[0]); f[5] = (short)f2bf(b1[1]);
            f[6] = (short)f2bf(b1[2]); f[7] = (short)f2bf(b1[3]);
            bfrag[ct][kc] = f;
        }

    unsigned short* hu = (unsigned short*)h;
    const int tiles_per_batch = Nn / 16;       // 1536
    for (int t = wib; t < tiles_per_batch; t += 1024) {
        const int row0 = batch * Nn + t * 16;
        const float* ap = x + (size_t)(row0 + lr) * 64 + kg;
        f32x4 a0 = *reinterpret_cast<const f32x4*>(ap);
        f32x4 a1 = *reinterpret_cast<const f32x4*>(ap + 4);
        f32x4 a2 = *reinterpret_cast<const f32x4*>(ap + 32);
        f32x4 a3 = *reinterpret_cast<const f32x4*>(ap + 36);
        s16x8 fa0, fa1;
        fa0[0] = (short)f2bf(a0[0]); fa0[1] = (short)f2bf(a0[1]);
        fa0[2] = (short)f2bf(a0[2]); fa0[3] = (short)f2bf(a0[3]);
        fa0[4] = (short)f2bf(a1[0]); fa0[5] = (short)f2bf(a1[1]);
        fa0[6] = (short)f2bf(a1[2]); fa0[7] = (short)f2bf(a1[3]);
        fa1[0] = (short)f2bf(a2[0]); fa1[1] = (short)f2bf(a2[1]);
        fa1[2] = (short)f2bf(a2[2]); fa1[3] = (short)f2bf(a2[3]);
        fa1[4] = (short)f2bf(a3[0]); fa1[5] = (short)f2bf(a3[1]);
        fa1[6] = (short)f2bf(a3[2]); fa1[7] = (short)f2bf(a3[3]);

        f32x4 acc[4];
#pragma unroll
        for (int ct = 0; ct < 4; ++ct) { acc[ct] = (f32x4){0.f, 0.f, 0.f, 0.f}; }
#pragma unroll
        for (int ct = 0; ct < 4; ++ct) {
            acc[ct] = __builtin_amdgcn_mfma_f32_16x16x32_bf16(fa0, bfrag[ct][0], acc[ct], 0, 0, 0);
            acc[ct] = __builtin_amdgcn_mfma_f32_16x16x32_bf16(fa1, bfrag[ct][1], acc[ct], 0, 0, 0);
        }
#pragma unroll
        for (int ct = 0; ct < 4; ++ct)
#pragma unroll
            for (int r = 0; r < 4; ++r)
                hu[(size_t)(row0 + dr + r) * 64 + ct * 16 + lr] = f2bf(acc[ct][r]);
    }
}

// ---------------------------------------------------------------------------
// K2: v[r][o] = (max_k h[nbr(r,k)][o]) - h[r][o], bf16 in/out.
// lane = channel; neighbor indices broadcast with READLANE (guaranteed SGPR)
// so every gather is scalar-base + lane*2 voffset: address math on SALU,
// no ds_bpermute latency on the dependency chain. 3-row groups -> 48
// gathers in flight. batch = bid%8 keeps gathers on the XCD whose L2
// holds the 3 MB h slice written by K1.
// ---------------------------------------------------------------------------
__global__ __launch_bounds__(256) void gather_bn_kernel(
    const __hip_bfloat16* __restrict__ h, const int* __restrict__ knn,
    __hip_bfloat16* __restrict__ v, float* __restrict__ stats)
{
    const int tid   = threadIdx.x;
    const int lane  = tid & 63;
    const int wave  = tid >> 6;
    const int batch = blockIdx.x & 7;
    const int qb    = blockIdx.x >> 3;
    const int wib   = qb * 4 + wave;           // 0..1023

    const unsigned short* hu = (const unsigned short*)h;
    unsigned short* vu = (unsigned short*)v;
    const int bbase = batch * Nn;
    const int kl    = lane & 15;

    float lsum = 0.f, lsq = 0.f;

    // each wave owns a contiguous 24-row chunk: 8 iterations x 3 rows
    const int rbase = bbase + wib * 24;
    for (int it = 0; it < 8; ++it) {
        const int r0 = rbase + it * 3;
        const int i0 = knn[(size_t)(r0 + 0) * Kk + kl];
        const int i1 = knn[(size_t)(r0 + 1) * Kk + kl];
        const int i2 = knn[(size_t)(r0 + 2) * Kk + kl];
        const float o0 = bf2f(hu[(size_t)(r0 + 0) * 64 + lane]);
        const float o1 = bf2f(hu[(size_t)(r0 + 1) * 64 + lane]);
        const float o2 = bf2f(hu[(size_t)(r0 + 2) * 64 + lane]);

        float m0 = -3e38f, m1 = -3e38f, m2 = -3e38f;
#pragma unroll
        for (int k = 0; k < Kk; ++k) {
            const int j0 = __builtin_amdgcn_readlane(i0, k);   // SGPR index
            const int j1 = __builtin_amdgcn_readlane(i1, k);
            const int j2 = __builtin_amdgcn_readlane(i2, k);
            m0 = fmaxf(m0, bf2f(hu[(size_t)(bbase + j0) * 64 + lane]));
            m1 = fmaxf(m1, bf2f(hu[(size_t)(bbase + j1) * 64 + lane]));
            m2 = fmaxf(m2, bf2f(hu[(size_t)(bbase + j2) * 64 + lane]));
        }
        const float v0 = m0 - o0;
        const float v1 = m1 - o1;
        const float v2 = m2 - o2;
        vu[(size_t)(r0 + 0) * 64 + lane] = f2bf(v0);
        vu[(size_t)(r0 + 1) * 64 + lane] = f2bf(v1);
        vu[(size_t)(r0 + 2) * 64 + lane] = f2bf(v2);
        lsum += v0 + v1 + v2;
        lsq  += v0 * v0 + v1 * v1 + v2 * v2;
    }

    __shared__ float s_sum[4][64];
    __shared__ float s_sq[4][64];
    s_sum[wave][lane] = lsum;
    s_sq[wave][lane]  = lsq;
    __syncthreads();
    if (wave == 0) {
        const float a = s_sum[0][lane] + s_sum[1][lane] + s_sum[2][lane] + s_sum[3][lane];
        const float q = s_sq[0][lane]  + s_sq[1][lane]  + s_sq[2][lane]  + s_sq[3][lane];
        atomicAdd(&stats[lane], a);
        atomicAdd(&stats[64 + lane], q);
    }
}

// ---------------------------------------------------------------------------
// K3: out = v_bf16 * scale[c] + shift[c]. scale/shift computed per-block
// from stats (trivial redundant work, saves a dispatch). Same batch
// partition: v read from the XCD L2 that K2 wrote through.
// ---------------------------------------------------------------------------
__global__ __launch_bounds__(256) void norm_kernel(
    const __hip_bfloat16* __restrict__ v, const float* __restrict__ stats,
    const float* __restrict__ gamma, const float* __restrict__ beta,
    float* __restrict__ out)
{
    __shared__ float sc[64], sh[64];
    if (threadIdx.x < 64) {
        const int o = threadIdx.x;
        const float inv = 1.0f / (float)Rr;
        const float mean = stats[o] * inv;
        const float var  = stats[64 + o] * inv - mean * mean;
        const float s    = gamma[o] * rsqrtf(var + EPS);
        sc[o] = s;
        sh[o] = beta[o] - mean * s;
    }
    __syncthreads();

    const int batch = blockIdx.x & 7;
    const int qb    = blockIdx.x >> 3;          // 0..255
    const u16x8* vu = (const u16x8*)v;
    const int per_batch8 = Nn * 64 / 8;         // groups of 8 elems per batch
    const size_t base8 = (size_t)batch * per_batch8;

    for (int li = qb * 256 + threadIdx.x; li < per_batch8; li += 256 * 256) {
        const size_t i = base8 + li;
        u16x8 t = vu[i];
        const int c = (li * 8) & 63;
        f32x4 r0, r1;
        r0[0] = bf2f(t[0]) * sc[c + 0] + sh[c + 0];
        r0[1] = bf2f(t[1]) * sc[c + 1] + sh[c + 1];
        r0[2] = bf2f(t[2]) * sc[c + 2] + sh[c + 2];
        r0[3] = bf2f(t[3]) * sc[c + 3] + sh[c + 3];
        r1[0] = bf2f(t[4]) * sc[c + 4] + sh[c + 4];
        r1[1] = bf2f(t[5]) * sc[c + 5] + sh[c + 5];
        r1[2] = bf2f(t[6]) * sc[c + 6] + sh[c + 6];
        r1[3] = bf2f(t[7]) * sc[c + 7] + sh[c + 7];
        f32x4* op = reinterpret_cast<f32x4*>(out + i * 8);
        __builtin_nontemporal_store(r0, op);
        __builtin_nontemporal_store(r1, op + 1);
    }
}

// ---------------------------------------------------------------------------
extern "C" void kernel_launch(void* const* d_in, const int* in_sizes, int n_in,
                              void* d_out, int out_size, void* d_ws, size_t ws_size,
                              hipStream_t stream)
{
    const float* x     = (const float*)d_in[0];
    const float* W     = (const float*)d_in[1];
    const float* gamma = (const float*)d_in[2];
    const float* beta  = (const float*)d_in[3];
    const int*   knn   = (const int*)d_in[4];
    float*       out   = (float*)d_out;

    // ws layout: h bf16 [Rr*64] | v bf16 [Rr*64] | stats[128]
    __hip_bfloat16* h = (__hip_bfloat16*)d_ws;
    __hip_bfloat16* v = h + (size_t)Rr * 64;
    float* stats = (float*)((char*)d_ws + 2 * (size_t)Rr * 64 * sizeof(__hip_bfloat16));

    linear_mfma_kernel<<<2048, 256, 0, stream>>>(x, W, h, stats);
    gather_bn_kernel<<<2048, 256, 0, stream>>>(h, knn, v, stats);
    norm_kernel<<<2048, 256, 0, stream>>>(v, stats, gamma, beta, out);
}